// Round 7
// baseline (208.408 us; speedup 1.0000x reference)
//
#include <hip/hip_runtime.h>
#include <hip/hip_bf16.h>

typedef float v4f __attribute__((ext_vector_type(4)));
typedef short v8s __attribute__((ext_vector_type(8)));

// ---- workspace layout ----
// float indices:
#define WS_STAT2   0        // 64   conv2 per-ic mean-of-max
#define WS_STATL   64       // 1024 (unused now; kept for layout stability)
#define WS_B1      1088     // 64
#define WS_B2      1152     // 64
#define WS_WL      1216     // 10240
#define WS_BL      11456    // 10
#define WS_IMAX    11520    // 2048 per-image max|x|
// byte offsets:
#define WS_W1F_B   54272    // 4096 bf16 conv1 weight frags [ot][q][m16][j], oc = m16*4+ot
#define WS_WP2_B   62464    // 25*64*64 bf16 conv2 weights, fragment order [uv][kc][ot][quad][m16][j]
#define WS_P1_B    267264   // 2048*144*64 bf16 pooled1 NHWC
#define WS_P2_B    38016000 // 2048*1024 fp32 pooled2
// scratch aliases (stream-ordered reuse, no extra footprint):
#define WS_C1MAX_F 9504000  // = P2 base as float idx; conv1 per-image ch-max [n][64]
#define WS_LPART_F 66816    // = P1 base as float idx; statl partials [64][1024]
// total ~46.4 MB (unchanged)

// per-image max|x|: 512 blocks x 4 waves, wave = 1 image.
__global__ void k_stat1(const float* __restrict__ x, float* ws) {
    int tid = threadIdx.x;
    int wv = tid >> 6, lane = tid & 63;
    int n = blockIdx.x * 4 + wv;
    const float* p = x + n * 784;
    float m = 0.f;
    for (int i = lane; i < 784; i += 64) m = fmaxf(m, fabsf(p[i]));
#pragma unroll
    for (int off = 32; off; off >>= 1) m = fmaxf(m, __shfl_xor(m, off, 64));
    if (lane == 0) ws[WS_IMAX + n] = m;
}

// conv1 SCINOL weights -> bf16 B-fragments [ot][q][m16][j] with oc = m16*4+ot
__global__ void k_prepw1(const float* __restrict__ w0, const float* __restrict__ S2,
                         const float* __restrict__ G, const float* __restrict__ eta,
                         const float* __restrict__ wM,
                         const float* __restrict__ b0, const float* __restrict__ bS2,
                         const float* __restrict__ bG, const float* __restrict__ beta,
                         float* ws) {
    __shared__ float red[256];
    int tid = threadIdx.x;
    float p = 0.f;
    for (int i = tid; i < 2048; i += 256) p += ws[WS_IMAX + i];
    red[tid] = p;
    __syncthreads();
    for (int s = 128; s > 0; s >>= 1) {
        if (tid < s) red[tid] += red[tid + s];
        __syncthreads();
    }
    float M = fmaxf(red[0] * (1.f / 2048.f), wM[0]);

    int i = blockIdx.x * 256 + tid;
    if (i < 4096) {
        int j = i & 7, m16 = (i >> 3) & 15, q = (i >> 7) & 3, ot = i >> 9;
        int tap = q * 8 + j, oc = m16 * 4 + ot;
        float v = 0.f;
        if (tap < 25) {
            int s = oc * 25 + tap;
            float g = G[s];
            float den = sqrtf(S2[s] + M * M);
            float inv = 1.f / den;
            float th = fminf(fmaxf(g * inv, -1.f), 1.f);
            v = w0[s] + ((g != 0.f) ? th * 0.5f * inv * eta[s] : 0.f);
        }
        ((__hip_bfloat16*)((char*)ws + WS_W1F_B))[i] = __float2bfloat16(v);
    } else if (i < 4160) {
        int c = i - 4096;
        float g = bG[c];
        float den = sqrtf(bS2[c] + 1.f);
        float inv = 1.f / den;
        float th = fminf(fmaxf(g * inv, -1.f), 1.f);
        ws[WS_B1 + c] = b0[c] + ((g != 0.f) ? th * 0.5f * inv * beta[c] : 0.f);
    }
}

// conv1 via MFMA implicit GEMM. Block = 256 thr (4 waves) = 1 image.
__global__ void __launch_bounds__(256)
k_conv1(const float* __restrict__ x, float* ws, __hip_bfloat16* __restrict__ pool1) {
    __shared__ __align__(16) float sX[1024];   // 28x28 image + zero pad
    __shared__ int sMax[64];
    int n = blockIdx.x, tid = threadIdx.x;
    int wv = tid >> 6, lane = tid & 63;
    int m16 = lane & 15, quad = lane >> 4;

    {   // stage image (784 floats) + zero pad to 1024
        const float4* src = (const float4*)(x + (size_t)n * 784);
        float4 v = {0.f, 0.f, 0.f, 0.f};
        if (tid < 196) v = src[tid];
        ((float4*)sX)[tid] = v;
    }
    if (tid < 64) sMax[tid] = 0;

    const ushort* wfrag = (const ushort*)((const char*)ws + WS_W1F_B);
    v8s bfr[4];
#pragma unroll
    for (int ot = 0; ot < 4; ++ot)
        bfr[ot] = *(const v8s*)(wfrag + ((ot * 4 + quad) * 16 + m16) * 8);
    float4 bias = *(const float4*)(ws + WS_B1 + m16 * 4);

    int dj[8];
#pragma unroll
    for (int j = 0; j < 8; ++j) {
        int tap = quad * 8 + j;
        int u = (tap * 13) >> 6;
        dj[j] = tap + 23 * u;
    }

    int W0 = wv * 36 + (m16 >> 2);
    int wy = (W0 * 171) >> 11;
    int wx = W0 - wy * 12;
    int coff = 28 * ((m16 >> 1) & 1) + (m16 & 1);

    __syncthreads();

    float vmax[4] = {0.f, 0.f, 0.f, 0.f};
    ushort* op = (ushort*)(pool1 + (size_t)n * 9216);

    float g[8];
    {
        int base = 56 * wy + 2 * wx + coff;
#pragma unroll
        for (int j = 0; j < 8; ++j) g[j] = sX[base + dj[j]];
    }
    for (int mt = 0; mt < 9; ++mt) {
        union { v8s v; ushort us[8]; } ua;
#pragma unroll
        for (int j = 0; j < 8; ++j)
            ua.us[j] = __bfloat16_as_ushort(__float2bfloat16(g[j]));

        wx += 4;
        if (wx >= 12) { wx -= 12; ++wy; }
        if (mt < 8) {
            int nb = 56 * wy + 2 * wx + coff;
#pragma unroll
            for (int j = 0; j < 8; ++j) g[j] = sX[nb + dj[j]];
        }

        v4f z = {0.f, 0.f, 0.f, 0.f};
        v4f acc[4];
#pragma unroll
        for (int ot = 0; ot < 4; ++ot)
            acc[ot] = __builtin_amdgcn_mfma_f32_16x16x32_bf16(ua.v, bfr[ot], z, 0, 0, 0);

        int Wd = (wv * 9 + mt) * 4 + quad;
        ushort4 pk;
#pragma unroll
        for (int ot = 0; ot < 4; ++ot) {
            v4f a = acc[ot];
            float m = fmaxf(fmaxf(a[0], a[1]), fmaxf(a[2], a[3]));
            float pv = fmaxf(m + bias[ot], 0.f);
            vmax[ot] = fmaxf(vmax[ot], pv);
            ((ushort*)&pk)[ot] = __bfloat16_as_ushort(__float2bfloat16(pv));
        }
        *(ushort4*)(op + Wd * 64 + m16 * 4) = pk;
    }

#pragma unroll
    for (int ot = 0; ot < 4; ++ot) {
        float m = vmax[ot];
        m = fmaxf(m, __shfl_xor(m, 16, 64));
        m = fmaxf(m, __shfl_xor(m, 32, 64));
        if (lane < 16) atomicMax(&sMax[lane * 4 + ot], __float_as_int(m));
    }
    __syncthreads();
    if (tid < 64) ws[WS_C1MAX_F + n * 64 + tid] = __int_as_float(sMax[tid]);
}

// reduce conv1 per-image channel maxima -> per-channel batch mean. 64 blocks, 1/ch.
__global__ void k_stat2red(float* ws) {
    __shared__ float red[256];
    int c = blockIdx.x, t = threadIdx.x;
    float s = 0.f;
    for (int n = t; n < 2048; n += 256) s += ws[WS_C1MAX_F + n * 64 + c];
    red[t] = s;
    __syncthreads();
    for (int k = 128; k > 0; k >>= 1) {
        if (t < k) red[t] += red[t + k];
        __syncthreads();
    }
    if (t == 0) ws[WS_STAT2 + c] = red[0] * (1.f / 2048.f);
}

// conv2 SCINOL weights -> bf16 in MFMA fragment order [uv][kc][ot][quad][m16][j]
__global__ void k_prepw2(const float* __restrict__ w0, const float* __restrict__ S2,
                         const float* __restrict__ G, const float* __restrict__ eta,
                         const float* __restrict__ wM,
                         const float* __restrict__ b0, const float* __restrict__ bS2,
                         const float* __restrict__ bG, const float* __restrict__ beta,
                         float* ws, __hip_bfloat16* __restrict__ wp2) {
    int i = blockIdx.x * 256 + threadIdx.x;  // exactly 102400
    int j = i & 7, m16 = (i >> 3) & 15, quad = (i >> 7) & 3;
    int ot = (i >> 9) & 3, kc = (i >> 11) & 1, uv = i >> 12;
    int oc = ot * 16 + m16, ic = kc * 32 + quad * 8 + j;
    int s = oc * 1600 + ic * 25 + uv;
    float M = fmaxf(ws[WS_STAT2 + ic], wM[ic]);
    float g = G[s];
    float den = sqrtf(S2[s] + M * M);
    float inv = 1.f / den;
    float th = fminf(fmaxf(g * inv, -1.f), 1.f);
    float v = w0[s] + ((g != 0.f) ? th * 0.5f * inv * eta[s] : 0.f);
    wp2[i] = __float2bfloat16(v);
    if (blockIdx.x == 0 && threadIdx.x < 64) {
        int c = threadIdx.x;
        float gb = bG[c];
        float den2 = sqrtf(bS2[c] + 1.f);
        float inv2 = 1.f / den2;
        float th2 = fminf(fmaxf(gb * inv2, -1.f), 1.f);
        ws[WS_B2 + c] = b0[c] + ((gb != 0.f) ? th2 * 0.5f * inv2 * beta[c] : 0.f);
    }
}

// conv2 implicit GEMM. Block = 128 thr (2 waves) = 2 images, wave = 1 image.
// A from LDS with XOR chunk swizzle (stride 64, no pad: phys 16B-chunk =
// chunk ^ (row&7)) -> conflict-free AND only 36.9 KB -> 4 blocks/CU = 2
// waves/SIMD, so the B-prefetch vmcnt stall is hidden by the SIMD-mate wave.
// B-fragments register double-buffered from global (L2-hot). No in-loop barriers.
__global__ void __launch_bounds__(128)
k_conv2(const ushort* __restrict__ pool1, const ushort* __restrict__ wp2,
        const float* __restrict__ ws, float* __restrict__ pool2) {
    __shared__ __align__(16) ushort sImg[2 * 9216];  // 2 images, 144 rows x 64, XOR-swizzled
    int tid = threadIdx.x;
    int wv = tid >> 6, lane = tid & 63;
    int n0 = blockIdx.x * 2;

    {   // stage 2 images: 288 rows x 8 uint4 chunks, phys chunk = col ^ (row&7)
        const uint4* src = (const uint4*)(pool1 + (size_t)n0 * 9216);
        uint4* dst = (uint4*)sImg;
#pragma unroll
        for (int i = 0; i < 18; ++i) {
            int c = tid + i * 128;          // 0..2303
            int r = c >> 3, col = c & 7;
            dst[r * 8 + (col ^ (r & 7))] = src[c];
        }
    }

    int m16 = lane & 15, quad = lane >> 4;
    int x0 = m16 & 7;
    int yb = m16 >> 3;
    v4f acc[4][4];
#pragma unroll
    for (int i = 0; i < 4; ++i)
#pragma unroll
        for (int j = 0; j < 4; ++j) acc[i][j] = (v4f){0.f, 0.f, 0.f, 0.f};

    // B-frag global base: offset = uv*4096 + (kc*4+ot)*512 + lane*8 (ushorts)
    const ushort* wlane = wp2 + lane * 8;
    v8s bf[2][2][4];
#pragma unroll
    for (int kc = 0; kc < 2; ++kc)
#pragma unroll
        for (int ot = 0; ot < 4; ++ot)
            bf[0][kc][ot] = *(const v8s*)(wlane + (kc * 4 + ot) * 512);

    __syncthreads();  // image staging only — the last barrier in this kernel

    const ushort* simg = sImg + wv * 9216;
#pragma unroll
    for (int uvIdx = 0; uvIdx < 25; ++uvIdx) {
        int cur = uvIdx & 1, nxt = cur ^ 1;
        if (uvIdx < 24) {
            const ushort* wnext = wlane + (uvIdx + 1) * 4096;
#pragma unroll
            for (int kc = 0; kc < 2; ++kc)
#pragma unroll
                for (int ot = 0; ot < 4; ++ot)
                    bf[nxt][kc][ot] = *(const v8s*)(wnext + (kc * 4 + ot) * 512);
        }
        int u = (uvIdx * 13) >> 6;       // uvIdx / 5
        int v = uvIdx - u * 5;
        v8s a[2][4];
#pragma unroll
        for (int kc = 0; kc < 2; ++kc)
#pragma unroll
            for (int pt = 0; pt < 4; ++pt) {
                int r = (pt * 2 + yb + u) * 12 + x0 + v;
                int chunk = (kc * 4 + quad) ^ (r & 7);
                a[kc][pt] = *(const v8s*)(simg + r * 64 + chunk * 8);
            }
#pragma unroll
        for (int kc = 0; kc < 2; ++kc)
#pragma unroll
            for (int pt = 0; pt < 4; ++pt)
#pragma unroll
                for (int ot = 0; ot < 4; ++ot)
                    acc[pt][ot] = __builtin_amdgcn_mfma_f32_16x16x32_bf16(
                        a[kc][pt], bf[cur][kc][ot], acc[pt][ot], 0, 0, 0);
    }

    // epilogue: bias + relu + 2x2 maxpool -> pooled2[n][oc*16+py*4+px] fp32
    int n = n0 + wv;
    float bv[4];
#pragma unroll
    for (int ot = 0; ot < 4; ++ot) bv[ot] = ws[WS_B2 + ot * 16 + m16];
    float* outp = pool2 + (size_t)n * 1024;
#pragma unroll
    for (int pt = 0; pt < 4; ++pt)
#pragma unroll
        for (int ot = 0; ot < 4; ++ot) {
            v4f a = acc[pt][ot];
            float m01 = fmaxf(a[0], a[1]);
            float m23 = fmaxf(a[2], a[3]);
            m01 = fmaxf(m01, __shfl_xor(m01, 32, 64));
            m23 = fmaxf(m23, __shfl_xor(m23, 32, 64));
            if (lane < 32) {
                int oc = ot * 16 + m16;
                int f = oc * 16 + pt * 4 + (quad & 1) * 2;
                outp[f] = fmaxf(m01 + bv[ot], 0.f);
                outp[f + 1] = fmaxf(m23 + bv[ot], 0.f);
            }
        }
}

// per-feature partial sums over batch; 64 blocks x 32 images, plain stores.
__global__ void k_statl(const float* __restrict__ pool2, float* ws) {
    int b = blockIdx.x, tid = threadIdx.x;
    float4 s = {0.f, 0.f, 0.f, 0.f};
    for (int im = 0; im < 32; ++im) {
        float4 v = ((const float4*)(pool2 + (size_t)(b * 32 + im) * 1024))[tid];
        s.x += v.x; s.y += v.y; s.z += v.z; s.w += v.w;
    }
    ((float4*)(ws + WS_LPART_F + b * 1024))[tid] = s;
}

// linear weights; folds the 64-partial statl reduction inline (no separate kernel)
__global__ void k_prepwl(const float* __restrict__ w0, const float* __restrict__ S2,
                         const float* __restrict__ G, const float* __restrict__ eta,
                         const float* __restrict__ wM,
                         const float* __restrict__ b0, const float* __restrict__ bS2,
                         const float* __restrict__ bG, const float* __restrict__ beta,
                         float* ws) {
    int i = blockIdx.x * 256 + threadIdx.x;
    if (i < 10240) {
        int f = i & 1023;
        float s = 0.f;
#pragma unroll
        for (int b = 0; b < 64; ++b) s += ws[WS_LPART_F + b * 1024 + f];
        float stat = s * (1.f / 2048.f);
        float M = fmaxf(wM[i], stat);
        float s2 = S2[i];
        float den = sqrtf(s2 + M * M);
        float inv = 1.f / den;
        float th = fminf(fmaxf(G[i] * inv, -1.f), 1.f);
        ws[WS_WL + i] = w0[i] + ((s2 != 0.f) ? th * 0.5f * inv * eta[i] : 0.f);  // cond = wS2 != 0
    } else if (i < 10250) {
        int c = i - 10240;
        float s2 = bS2[c];
        float den = sqrtf(s2 + 1.f);
        float inv = 1.f / den;
        float th = fminf(fmaxf(bG[c] * inv, -1.f), 1.f);
        ws[WS_BL + c] = b0[c] + ((s2 != 0.f) ? th * 0.5f * inv * beta[c] : 0.f);  // cond = bS2 != 0
    }
}

// (2048,1024) x (1024,10)^T + b: wave per image, lane-strided features
__global__ void k_linear(const float* __restrict__ pool2, const float* __restrict__ ws,
                         float* __restrict__ out) {
    int tid = threadIdx.x;
    int wv = tid >> 6, lane = tid & 63;
    int n = blockIdx.x * 4 + wv;
    const float* hp = pool2 + (size_t)n * 1024;
    float h[16];
#pragma unroll
    for (int j = 0; j < 16; ++j) h[j] = hp[j * 64 + lane];
    for (int oc = 0; oc < 10; ++oc) {
        const float* wp = ws + WS_WL + oc * 1024;
        float d = 0.f;
#pragma unroll
        for (int j = 0; j < 16; ++j) d = fmaf(h[j], wp[j * 64 + lane], d);
#pragma unroll
        for (int off = 32; off; off >>= 1) d += __shfl_xor(d, off, 64);
        if (lane == 0) out[n * 10 + oc] = d + ws[WS_BL + oc];
    }
}

extern "C" void kernel_launch(void* const* d_in, const int* in_sizes, int n_in,
                              void* d_out, int out_size, void* d_ws, size_t ws_size,
                              hipStream_t stream) {
    const float* x = (const float*)d_in[0];
    float* ws = (float*)d_ws;
    __hip_bfloat16* wp2 = (__hip_bfloat16*)((char*)d_ws + WS_WP2_B);
    __hip_bfloat16* p1 = (__hip_bfloat16*)((char*)d_ws + WS_P1_B);
    float* p2 = (float*)((char*)d_ws + WS_P2_B);
    float* out = (float*)d_out;

    k_stat1<<<512, 256, 0, stream>>>(x, ws);
    k_prepw1<<<17, 256, 0, stream>>>(
        (const float*)d_in[1], (const float*)d_in[2], (const float*)d_in[3],
        (const float*)d_in[4], (const float*)d_in[5], (const float*)d_in[6],
        (const float*)d_in[7], (const float*)d_in[8], (const float*)d_in[9], ws);
    k_conv1<<<2048, 256, 0, stream>>>(x, ws, p1);
    k_stat2red<<<64, 256, 0, stream>>>(ws);
    k_prepw2<<<400, 256, 0, stream>>>(
        (const float*)d_in[10], (const float*)d_in[11], (const float*)d_in[12],
        (const float*)d_in[13], (const float*)d_in[14], (const float*)d_in[15],
        (const float*)d_in[16], (const float*)d_in[17], (const float*)d_in[18], ws, wp2);
    k_conv2<<<1024, 128, 0, stream>>>((const ushort*)p1, (const ushort*)wp2, ws, p2);
    k_statl<<<64, 256, 0, stream>>>(p2, ws);
    k_prepwl<<<41, 256, 0, stream>>>(
        (const float*)d_in[19], (const float*)d_in[20], (const float*)d_in[21],
        (const float*)d_in[22], (const float*)d_in[23], (const float*)d_in[24],
        (const float*)d_in[25], (const float*)d_in[26], (const float*)d_in[27], ws);
    k_linear<<<512, 256, 0, stream>>>(p2, ws, out);
}